// Round 7
// baseline (431.615 us; speedup 1.0000x reference)
//
#include <hip/hip_runtime.h>
#include <math.h>

// ---------------------------------------------------------------------------
// QuantumEncoderLayer R7: K-loop address strength-reduction.
//   gemm_mfma / attn_mfma: swizzled global_load_lds source addresses hoisted
//   out of the K-loop (loop-carried pointers, +const per iter); LDS dst
//   offsets loop-invariant. Removes ~70 VALU inst per thread per K-iter that
//   sat serially between barriers (R6: VALUBusy 3x MfmaUtil, both low).
//   Everything else identical to R6 (xor-swizzled conflict-free LDS, fast
//   GELU, fused |phi|^2, bf16 residual stream).
// ---------------------------------------------------------------------------

typedef __bf16 bf16;
typedef bf16 bf16x8 __attribute__((ext_vector_type(8)));
typedef bf16 bf16x4 __attribute__((ext_vector_type(4)));
typedef float f32x4 __attribute__((ext_vector_type(4)));

__device__ __forceinline__ void gld16(const void* g, void* l) {
  __builtin_amdgcn_global_load_lds(
      (__attribute__((address_space(1))) void*)(void*)g,
      (__attribute__((address_space(3))) void*)l, 16, 0, 0);
}

__device__ __forceinline__ float waveAllSum(float v) {
#pragma unroll
  for (int m = 1; m < 64; m <<= 1) v += __shfl_xor(v, m, 64);
  return v;
}

__device__ __forceinline__ float fast_gelu(float v) {
  float u = 0.79788456080286536f * v * (1.0f + 0.044715f * v * v);
  return v / (1.0f + __expf(-2.0f * u));
}

// ---------------------------------------------------------------------------
__global__ __launch_bounds__(256) void cvt_all(
    const float* __restrict__ x, const float* __restrict__ w1,
    const float* __restrict__ w2, const float* __restrict__ w3,
    const float* __restrict__ w4, bf16* __restrict__ xb,
    bf16* __restrict__ b1, bf16* __restrict__ b2, bf16* __restrict__ b3,
    bf16* __restrict__ b4) {
  int i = blockIdx.x * 256 + threadIdx.x;
  const float* src;
  bf16* dst;
  int off;
  if (i < 2097152) {
    src = x; dst = xb; off = i;
  } else if (i < 2097152 + 196608) {
    src = w1; dst = b1; off = i - 2097152;
  } else if (i < 2097152 + 196608 + 65536) {
    src = w2; dst = b2; off = i - (2097152 + 196608);
  } else if (i < 2097152 + 196608 + 65536 + 262144) {
    src = w3; dst = b3; off = i - (2097152 + 196608 + 65536);
  } else {
    src = w4; dst = b4; off = i - (2097152 + 196608 + 65536 + 262144);
  }
  float4 v = ((const float4*)src)[off];
  bf16x4 o = {(bf16)v.x, (bf16)v.y, (bf16)v.z, (bf16)v.w};
  ((bf16x4*)dst)[off] = o;
}

// ---------------------------------------------------------------------------
// Wp (512x512 bf16 packed complex, interleaved cols: 2j -> Re_j, 2j+1 -> Im_j)
// ---------------------------------------------------------------------------
__global__ __launch_bounds__(256) void make_W(const float* __restrict__ qw,
                                              bf16* __restrict__ Wp) {
  __shared__ float gates[32 * 8];
  int tid = threadIdx.x, lane = tid & 63;
  if (tid < 32) {
    int l = tid >> 3, i = tid & 7;
    float ax = qw[l * 16 + i] * 0.5f;
    float az = qw[l * 16 + 8 + i] * 0.5f;
    float cx, sx, cz, sz;
    sincosf(ax, &sx, &cx);
    sincosf(az, &sz, &cz);
    float* g = gates + tid * 8;
    g[0] = cz * cx;   g[1] = -sz * cx;
    g[2] = -sz * sx;  g[3] = -cz * sx;
    g[4] = sz * sx;   g[5] = -cz * sx;
    g[6] = cz * cx;   g[7] = sz * cx;
  }
  __syncthreads();
  int k = blockIdx.x * 4 + (tid >> 6);

  float sr[4], si[4];
#pragma unroll
  for (int l = 0; l < 4; ++l) {
    sr[l] = (lane * 4 + l == k) ? 1.0f : 0.0f;
    si[l] = 0.0f;
  }

  auto gate = [&](int p, float u00r, float u00i, float u01r, float u01i,
                  float u10r, float u10i, float u11r, float u11i) {
    if (p >= 2) {
      int m = 1 << (p - 2);
      int b = (lane >> (p - 2)) & 1;
      float csr = b ? u11r : u00r;
      float csi = b ? u11i : u00i;
      float cor = b ? u10r : u01r;
      float coi = b ? u10i : u01i;
#pragma unroll
      for (int l = 0; l < 4; ++l) {
        float pr = __shfl_xor(sr[l], m, 64);
        float pi = __shfl_xor(si[l], m, 64);
        float nr = fmaf(csr, sr[l],
                        fmaf(-csi, si[l], fmaf(cor, pr, -coi * pi)));
        float ni = fmaf(csr, si[l],
                        fmaf(csi, sr[l], fmaf(cor, pi, coi * pr)));
        sr[l] = nr;
        si[l] = ni;
      }
    } else {
      float nr[4], ni[4];
#pragma unroll
      for (int l = 0; l < 4; ++l) {
        int b = (l >> p) & 1;
        int pl = l ^ (1 << p);
        float csr = b ? u11r : u00r;
        float csi = b ? u11i : u00i;
        float cor = b ? u10r : u01r;
        float coi = b ? u10i : u01i;
        nr[l] = fmaf(csr, sr[l],
                     fmaf(-csi, si[l], fmaf(cor, sr[pl], -coi * si[pl])));
        ni[l] = fmaf(csr, si[l],
                     fmaf(csi, sr[l], fmaf(cor, si[pl], coi * sr[pl])));
      }
#pragma unroll
      for (int l = 0; l < 4; ++l) {
        sr[l] = nr[l];
        si[l] = ni[l];
      }
    }
  };
  auto docnot = [&](int i) {
    int pc = 7 - i, pt = 6 - i;
    if (pt >= 2) {
      int ctrl = (lane >> (pc - 2)) & 1;
      int m = 1 << (pt - 2);
#pragma unroll
      for (int l = 0; l < 4; ++l) {
        float pr = __shfl_xor(sr[l], m, 64);
        float pi = __shfl_xor(si[l], m, 64);
        if (ctrl) {
          sr[l] = pr;
          si[l] = pi;
        }
      }
    } else if (pt == 1) {
      if (lane & 1) {
        float t;
        t = sr[0]; sr[0] = sr[2]; sr[2] = t;
        t = si[0]; si[0] = si[2]; si[2] = t;
        t = sr[1]; sr[1] = sr[3]; sr[3] = t;
        t = si[1]; si[1] = si[3]; si[3] = t;
      }
    } else {
      float t;
      t = sr[2]; sr[2] = sr[3]; sr[3] = t;
      t = si[2]; si[2] = si[3]; si[3] = t;
    }
  };

  for (int l = 0; l < 4; ++l) {
    for (int i = 0; i < 8; ++i) {
      const float* g = gates + (l * 8 + i) * 8;
      gate(7 - i, g[0], g[1], g[2], g[3], g[4], g[5], g[6], g[7]);
    }
    for (int i = 0; i < 7; ++i) docnot(i);
  }

#pragma unroll
  for (int l = 0; l < 4; ++l) {
    int j = lane * 4 + l;
    Wp[(2 * j) * 512 + k] = (bf16)sr[l];
    Wp[(2 * j) * 512 + 256 + k] = (bf16)(-si[l]);
    Wp[(2 * j + 1) * 512 + k] = (bf16)si[l];
    Wp[(2 * j + 1) * 512 + 256 + k] = (bf16)sr[l];
  }
}

// ---------------------------------------------------------------------------
__global__ __launch_bounds__(256) void make_Q(const float* __restrict__ qout_w,
                                              bf16* __restrict__ Q) {
  int t = blockIdx.x * 256 + threadIdx.x;
  int col = t >> 8, k = t & 255;
  float s = 0.f;
#pragma unroll
  for (int w = 0; w < 8; ++w) {
    float sg = ((k >> (7 - w)) & 1) ? -1.0f : 1.0f;
    s = fmaf(qout_w[col * 8 + w], sg, s);
  }
  Q[col * 256 + k] = (bf16)s;
}

// ---------------------------------------------------------------------------
// C[M,N] = A[M,K] @ W[N,K]^T (+bias). BK=64, xor-swizzled LDS, hoisted
// staging pointers. modes: 1 gelu | 2 qkv-split | 4 residual | 5 plain |
// 6 prob-fused.
// ---------------------------------------------------------------------------
__global__ __launch_bounds__(256) void gemm_mfma(
    const bf16* __restrict__ A, const bf16* __restrict__ W,
    const float* __restrict__ bias, const bf16* __restrict__ Xadd,
    bf16* __restrict__ Cb, bf16* __restrict__ qk, bf16* __restrict__ vT,
    bf16* __restrict__ prob, int M, int N, int K, int mode) {
  __shared__ __align__(16) bf16 As[128 * 64];
  __shared__ __align__(16) bf16 Bs[128 * 64];
  int tid = threadIdx.x;
  int lane = tid & 63, w = tid >> 6;
  int wr = w >> 1, wc = w & 1;
  int quad = lane >> 4, lc = lane & 15;
  long m0 = (long)blockIdx.x * 128;
  long n0 = (long)blockIdx.y * 128;
  f32x4 acc[4][4] = {};
  int sl0 = w * 256 + lane;

  // hoisted staging pointers (advance by BK=64 elements per iter)
  const bf16* aSrc[4];
  const bf16* bSrc[4];
  int ldsOff[4];
#pragma unroll
  for (int c = 0; c < 4; ++c) {
    int slot = sl0 + c * 64;
    int row = slot >> 3, g = slot & 7;
    int sc = (g ^ (row & 7)) << 3;
    aSrc[c] = A + (m0 + row) * (long)K + sc;
    bSrc[c] = W + (n0 + row) * (long)K + sc;
    ldsOff[c] = slot << 3;
  }

  for (int k0 = 0; k0 < K; k0 += 64) {
    __syncthreads();
#pragma unroll
    for (int c = 0; c < 4; ++c) {
      gld16(aSrc[c], &As[ldsOff[c]]);
      gld16(bSrc[c], &Bs[ldsOff[c]]);
      aSrc[c] += 64;
      bSrc[c] += 64;
    }
    __syncthreads();
#pragma unroll
    for (int t = 0; t < 2; ++t) {
      bf16x8 af[4], bfr[4];
      int pg = ((t * 4 + quad) ^ (lc & 7)) << 3;
#pragma unroll
      for (int i = 0; i < 4; ++i) {
        af[i] = *(const bf16x8*)&As[(wr * 64 + i * 16 + lc) * 64 + pg];
        bfr[i] = *(const bf16x8*)&Bs[(wc * 64 + i * 16 + lc) * 64 + pg];
      }
#pragma unroll
      for (int i = 0; i < 4; ++i)
#pragma unroll
        for (int j = 0; j < 4; ++j)
          acc[i][j] = __builtin_amdgcn_mfma_f32_16x16x32_bf16(
              af[i], bfr[j], acc[i][j], 0, 0, 0);
    }
  }

#pragma unroll
  for (int i = 0; i < 4; ++i) {
    long grow0 = m0 + wr * 64 + i * 16 + quad * 4;
#pragma unroll
    for (int j = 0; j < 4; ++j) {
      long col = n0 + wc * 64 + j * 16 + lc;
      float bv = (mode == 6) ? 0.f : bias[col];
      float v[4];
#pragma unroll
      for (int r = 0; r < 4; ++r) v[r] = acc[i][j][r] + bv;
      if (mode == 1) {
#pragma unroll
        for (int r = 0; r < 4; ++r)
          Cb[(grow0 + r) * N + col] = (bf16)fast_gelu(v[r]);
      } else if (mode == 4) {
#pragma unroll
        for (int r = 0; r < 4; ++r)
          Cb[(grow0 + r) * N + col] =
              (bf16)(v[r] + (float)Xadd[(grow0 + r) * N + col]);
      } else if (mode == 5) {
#pragma unroll
        for (int r = 0; r < 4; ++r) Cb[(grow0 + r) * N + col] = (bf16)v[r];
      } else if (mode == 6) {
        float pv[4];
#pragma unroll
        for (int r = 0; r < 4; ++r) pv[r] = v[r] * v[r];
#pragma unroll
        for (int r = 0; r < 4; ++r) pv[r] += __shfl_xor(pv[r], 1, 64);
        if (!(lc & 1)) {
          long pc = col >> 1;
#pragma unroll
          for (int r = 0; r < 4; ++r)
            prob[(grow0 + r) * 256 + pc] = (bf16)pv[r];
        }
      } else {  // mode 2
        if (col < 1024) {
#pragma unroll
          for (int r = 0; r < 4; ++r) qk[(grow0 + r) * 1024 + col] = (bf16)v[r];
        } else {
          int hh = (int)((col - 1024) >> 7);
          int dd = (int)((col - 1024) & 127);
          long bidx = grow0 >> 9;
          int s0 = (int)(grow0 & 511);
          bf16x4 pk = {(bf16)v[0], (bf16)v[1], (bf16)v[2], (bf16)v[3]};
          *(bf16x4*)&vT[(((bidx << 2) + hh) * 128 + dd) * 512 + s0] = pk;
        }
      }
    }
  }
}

// ---------------------------------------------------------------------------
// Flash attention (xor-swizzled, no-max softmax, __expf), hoisted staging.
// ---------------------------------------------------------------------------
__global__ __launch_bounds__(256) void attn_mfma(const bf16* __restrict__ qk,
                                                 const bf16* __restrict__ vT,
                                                 bf16* __restrict__ o) {
  __shared__ __align__(16) bf16 Ks[64 * 128];
  __shared__ __align__(16) bf16 Vt[128 * 64];
  __shared__ __align__(16) bf16 Ps[4][64 * 16];
  int tid = threadIdx.x, lane = tid & 63, w = tid >> 6;
  int quad = lane >> 4, lc = lane & 15;
  int bh = blockIdx.x, b = bh >> 2, h = bh & 3;
  int q0 = blockIdx.y * 64 + w * 16;
  const float scale = 0.08838834764831845f;

  bf16x8 qf[4];
  {
    const bf16* qp =
        qk + ((long)(b * 512 + q0 + lc)) * 1024 + h * 128 + quad * 8;
#pragma unroll
    for (int ks = 0; ks < 4; ++ks) qf[ks] = *(const bf16x8*)(qp + ks * 32);
  }
  f32x4 oacc[8] = {};
  float lrun[4] = {0.f, 0.f, 0.f, 0.f};

  const bf16* kbase = qk + (long)b * 512 * 1024 + 512 + h * 128;
  const bf16* vbase = vT + (long)bh * 128 * 512;
  int sl0 = w * 256 + lane;

  // hoisted staging pointers: K advances 64 rows (64*1024 elems), V advances
  // 64 cols per iter.
  const bf16* kSrc[4];
  const bf16* vSrc[4];
  int kOff[4], vOff[4];
#pragma unroll
  for (int c = 0; c < 4; ++c) {
    int slot = sl0 + c * 64;
    {
      int row = slot >> 4, g = slot & 15;
      kSrc[c] = kbase + (long)row * 1024 + ((g ^ (row & 15)) << 3);
      kOff[c] = slot << 3;
    }
    {
      int row = slot >> 3, g = slot & 7;
      vSrc[c] = vbase + (long)row * 512 + ((g ^ (row & 7)) << 3);
      vOff[c] = slot << 3;
    }
  }

  for (int kt = 0; kt < 512; kt += 64) {
    __syncthreads();
#pragma unroll
    for (int c = 0; c < 4; ++c) {
      gld16(kSrc[c], &Ks[kOff[c]]);
      gld16(vSrc[c], &Vt[vOff[c]]);
      kSrc[c] += 64 * 1024;
      vSrc[c] += 64;
    }
    __syncthreads();

    float p[4][4];
#pragma unroll
    for (int c = 0; c < 4; ++c) {
      f32x4 a = {};
#pragma unroll
      for (int ks = 0; ks < 4; ++ks) {
        bf16x8 kf = *(const bf16x8*)&Ks[(c * 16 + lc) * 128 +
                                        (((ks * 4 + quad) ^ lc) << 3)];
        a = __builtin_amdgcn_mfma_f32_16x16x32_bf16(qf[ks], kf, a, 0, 0, 0);
      }
#pragma unroll
      for (int r = 0; r < 4; ++r) p[c][r] = a[r] * scale;
    }

#pragma unroll
    for (int r = 0; r < 4; ++r) {
      float rs = 0.f;
#pragma unroll
      for (int c = 0; c < 4; ++c) {
        float e = __expf(p[c][r]);
        p[c][r] = e;
        rs += e;
      }
#pragma unroll
      for (int m = 1; m < 16; m <<= 1) rs += __shfl_xor(rs, m, 64);
      lrun[r] += rs;
    }

#pragma unroll
    for (int c = 0; c < 4; ++c) {
      bf16x4 pk = {(bf16)p[c][0], (bf16)p[c][1], (bf16)p[c][2], (bf16)p[c][3]};
      *(bf16x4*)&Ps[w][(c * 16 + lc) * 16 + ((quad ^ (lc & 3)) << 2)] = pk;
    }
    bf16x8 pf[2];
#pragma unroll
    for (int kc = 0; kc < 2; ++kc) {
      bf16x8 t;
#pragma unroll
      for (int jj = 0; jj < 8; ++jj) {
        int row = kc * 32 + quad * 8 + jj;
        t[jj] = Ps[w][row * 16 + (((lc >> 2) ^ (row & 3)) << 2) + (lc & 3)];
      }
      pf[kc] = t;
    }
#pragma unroll
    for (int n = 0; n < 8; ++n)
#pragma unroll
      for (int kc = 0; kc < 2; ++kc) {
        bf16x8 vf = *(const bf16x8*)&Vt[(n * 16 + lc) * 64 +
                                        (((kc * 4 + quad) ^ (lc & 7)) << 3)];
        oacc[n] =
            __builtin_amdgcn_mfma_f32_16x16x32_bf16(pf[kc], vf, oacc[n], 0, 0, 0);
      }
  }

  float linv[4];
#pragma unroll
  for (int r = 0; r < 4; ++r) linv[r] = 1.0f / lrun[r];
  bf16* op = o + ((long)(b * 512 + q0 + quad * 4)) * 512 + h * 128 + lc;
#pragma unroll
  for (int n = 0; n < 8; ++n)
#pragma unroll
    for (int r = 0; r < 4; ++r)
      op[(long)r * 512 + n * 16] = (bf16)(oacc[n][r] * linv[r]);
}

// ---------------------------------------------------------------------------
__global__ __launch_bounds__(256) void add_ln_bb(
    const bf16* __restrict__ a, const bf16* __restrict__ b,
    const float* __restrict__ g, const float* __restrict__ be,
    float* __restrict__ out) {
  long row = (blockIdx.x * 256 + threadIdx.x) >> 6;
  int lane = threadIdx.x & 63;
  const bf16* ar = a + row * 512;
  const bf16* br = b + row * 512;
  float v[8];
  float s = 0.f;
#pragma unroll
  for (int j = 0; j < 8; ++j) {
    int c = lane + 64 * j;
    v[j] = (float)ar[c] + (float)br[c];
    s += v[j];
  }
  s = waveAllSum(s);
  float mean = s * (1.0f / 512.0f);
  float var = 0.f;
#pragma unroll
  for (int j = 0; j < 8; ++j) {
    float d = v[j] - mean;
    var = fmaf(d, d, var);
  }
  var = waveAllSum(var);
  float rstd = rsqrtf(var * (1.0f / 512.0f) + 1e-5f);
  float* orow = out + row * 512;
#pragma unroll
  for (int j = 0; j < 8; ++j) {
    int c = lane + 64 * j;
    orow[c] = (v[j] - mean) * rstd * g[c] + be[c];
  }
}

// ---------------------------------------------------------------------------
__global__ __launch_bounds__(256) void quantum_pre(
    const bf16* __restrict__ xb, const bf16* __restrict__ attnpb,
    const float* __restrict__ g1, const float* __restrict__ b1,
    const float* __restrict__ g3, const float* __restrict__ b3,
    const float* __restrict__ qin_w, const float* __restrict__ qin_b,
    bf16* __restrict__ x1out, bf16* __restrict__ psi) {
  long row = (blockIdx.x * 256 + threadIdx.x) >> 6;
  int lane = threadIdx.x & 63;
  const bf16* xr = xb + row * 512;
  const bf16* ar = attnpb + row * 512;

  float x1v[8];
  {
    float s = 0.f;
#pragma unroll
    for (int j = 0; j < 8; ++j) {
      int c = lane + 64 * j;
      x1v[j] = (float)xr[c] + (float)ar[c];
      s += x1v[j];
    }
    s = waveAllSum(s);
    float mean = s * (1.0f / 512.0f);
    float var = 0.f;
#pragma unroll
    for (int j = 0; j < 8; ++j) {
      float d = x1v[j] - mean;
      var = fmaf(d, d, var);
    }
    var = waveAllSum(var);
    float rstd = rsqrtf(var * (1.0f / 512.0f) + 1e-5f);
#pragma unroll
    for (int j = 0; j < 8; ++j) {
      int c = lane + 64 * j;
      x1v[j] = (x1v[j] - mean) * rstd * g1[c] + b1[c];
    }
  }
  bf16* x1row = x1out + row * 512;
#pragma unroll
  for (int j = 0; j < 8; ++j) x1row[lane + 64 * j] = (bf16)x1v[j];

  float xn[8];
  {
    float s = 0.f;
#pragma unroll
    for (int j = 0; j < 8; ++j) s += x1v[j];
    s = waveAllSum(s);
    float mean = s * (1.0f / 512.0f);
    float var = 0.f;
#pragma unroll
    for (int j = 0; j < 8; ++j) {
      float d = x1v[j] - mean;
      var = fmaf(d, d, var);
    }
    var = waveAllSum(var);
    float rstd = rsqrtf(var * (1.0f / 512.0f) + 1e-5f);
#pragma unroll
    for (int j = 0; j < 8; ++j) {
      int c = lane + 64 * j;
      xn[j] = (x1v[j] - mean) * rstd * g3[c] + b3[c];
    }
  }

  float ang[8];
#pragma unroll
  for (int w = 0; w < 8; ++w) {
    float p = 0.f;
#pragma unroll
    for (int j = 0; j < 8; ++j)
      p = fmaf(xn[j], qin_w[w * 512 + lane + 64 * j], p);
    p = waveAllSum(p);
    ang[w] = p + qin_b[w];
  }

  float v0r[8], v0i[8], v1r[8];
#pragma unroll
  for (int i = 0; i < 8; ++i) {
    float h = ang[i] * 0.5f;
    float c, s;
    sincosf(h, &s, &c);
    v0r[i] = c * c;
    v0i[i] = -c * s;
    v1r[i] = s * s;
  }

  float Pr, Pi;
  {
    int bit0 = (lane >> 5) & 1;
    Pr = bit0 ? v1r[0] : v0r[0];
    Pi = v0i[0];
#pragma unroll
    for (int i = 1; i < 6; ++i) {
      int bit = (lane >> (5 - i)) & 1;
      float br = bit ? v1r[i] : v0r[i];
      float bi = v0i[i];
      float nr = Pr * br - Pi * bi;
      float ni = Pr * bi + Pi * br;
      Pr = nr;
      Pi = ni;
    }
  }

  bf16 rebuf[4], imbuf[4];
#pragma unroll
  for (int l = 0; l < 4; ++l) {
    int b6 = (l >> 1) & 1, b7 = l & 1;
    float br = b6 ? v1r[6] : v0r[6], bi = v0i[6];
    float tr = Pr * br - Pi * bi;
    float ti = Pr * bi + Pi * br;
    float cr = b7 ? v1r[7] : v0r[7], ci = v0i[7];
    float fr = tr * cr - ti * ci;
    float fi = tr * ci + ti * cr;
    rebuf[l] = (bf16)fr;
    imbuf[l] = (bf16)fi;
  }
  bf16* prow = psi + row * 512;
  *(bf16x4*)&prow[lane * 4] = *(bf16x4*)rebuf;
  *(bf16x4*)&prow[256 + lane * 4] = *(bf16x4*)imbuf;
}

// ---------------------------------------------------------------------------
extern "C" void kernel_launch(void* const* d_in, const int* in_sizes, int n_in,
                              void* d_out, int out_size, void* d_ws,
                              size_t ws_size, hipStream_t stream) {
  const float* x = (const float*)d_in[0];
  const float* attn_in_w = (const float*)d_in[1];
  const float* attn_in_b = (const float*)d_in[2];
  const float* attn_out_w = (const float*)d_in[3];
  const float* attn_out_b = (const float*)d_in[4];
  const float* ln1_g = (const float*)d_in[5];
  const float* ln1_b = (const float*)d_in[6];
  const float* ln2_g = (const float*)d_in[7];
  const float* ln2_b = (const float*)d_in[8];
  const float* ln3_g = (const float*)d_in[9];
  const float* ln3_b = (const float*)d_in[10];
  const float* qin_w = (const float*)d_in[11];
  const float* qin_b = (const float*)d_in[12];
  const float* qweights = (const float*)d_in[13];
  const float* qout_w = (const float*)d_in[14];
  const float* qout_b = (const float*)d_in[15];
  const float* ffn_w1 = (const float*)d_in[16];
  const float* ffn_b1 = (const float*)d_in[17];
  const float* ffn_w2 = (const float*)d_in[18];
  const float* ffn_b2 = (const float*)d_in[19];

  char* wsB = (char*)d_ws;
  bf16* qkb = (bf16*)(wsB);                      // 32 MB (B,S,1024)
  bf16* vtb = (bf16*)(wsB + (32L << 20));        // 16 MB (B,H,128,512)
  bf16* ob = (bf16*)(wsB + (48L << 20));         // 16 MB (B,S,512)
  bf16* hb = (bf16*)(wsB);                       // 64 MB overlay (qkv dead)
  bf16* attnpb = (bf16*)(wsB + (64L << 20));     // 16 MB
  bf16* psi = (bf16*)(wsB + (80L << 20));        // 16 MB
  bf16* x1b = (bf16*)(wsB + (96L << 20));        // 16 MB
  bf16* probb = (bf16*)(wsB + (112L << 20));     // 8 MB
  bf16* x2b = (bf16*)(wsB + (120L << 20));       // 16 MB
  bf16* f2outb = (bf16*)(wsB + (136L << 20));    // 16 MB
  bf16* xb = (bf16*)(wsB + (152L << 20));        // 16 MB
  bf16* w_in = (bf16*)(wsB + (168L << 20));      // 1.5 MB
  bf16* w_out = (bf16*)(wsB + (170L << 20));     // 0.5 MB
  bf16* w_f1 = (bf16*)(wsB + (171L << 20));      // 2 MB
  bf16* w_f2 = (bf16*)(wsB + (173L << 20));      // 2 MB
  bf16* Wp = (bf16*)(wsB + (176L << 20));        // 512 KB
  bf16* Qm = (bf16*)(wsB + (177L << 20));        // 256 KB

  const int M = 16384;
  float* outp = (float*)d_out;

  cvt_all<<<11264, 256, 0, stream>>>(x, attn_in_w, attn_out_w, ffn_w1, ffn_w2,
                                     xb, w_in, w_out, w_f1, w_f2);
  make_W<<<64, 256, 0, stream>>>(qweights, Wp);
  make_Q<<<512, 256, 0, stream>>>(qout_w, Qm);

  // 1. QKV projection (split epilogue)
  gemm_mfma<<<dim3(M / 128, 12), 256, 0, stream>>>(
      xb, w_in, attn_in_b, nullptr, nullptr, qkb, vtb, nullptr, M, 1536, 512,
      2);
  // 2. attention
  attn_mfma<<<dim3(128, 8), 256, 0, stream>>>(qkb, vtb, ob);
  // 3. output projection -> bf16
  gemm_mfma<<<dim3(M / 128, 4), 256, 0, stream>>>(
      ob, w_out, attn_out_b, nullptr, attnpb, nullptr, nullptr, nullptr, M,
      512, 512, 5);
  // 4. quantum_pre: x1b + psi
  quantum_pre<<<dim3(M / 4), 256, 0, stream>>>(xb, attnpb, ln1_g, ln1_b,
                                               ln3_g, ln3_b, qin_w, qin_b,
                                               x1b, psi);
  // 5. prob = |Psi @ Wp^T|^2 (fused epilogue)
  gemm_mfma<<<dim3(M / 128, 4), 256, 0, stream>>>(
      psi, Wp, nullptr, nullptr, nullptr, nullptr, nullptr, probb, M, 512,
      512, 6);
  // 6. x2 = x1 + prob @ Q^T + qout_b -> bf16
  gemm_mfma<<<dim3(M / 128, 4), 256, 0, stream>>>(
      probb, Qm, qout_b, x1b, x2b, nullptr, nullptr, nullptr, M, 512, 256, 4);
  // 7. h = fast_gelu(x2 @ ffn_w1^T + b1) -> bf16
  gemm_mfma<<<dim3(M / 128, 16), 256, 0, stream>>>(
      x2b, w_f1, ffn_b1, nullptr, hb, nullptr, nullptr, nullptr, M, 2048, 512,
      1);
  // 8. ffn_out = h @ ffn_w2^T + b2 -> bf16
  gemm_mfma<<<dim3(M / 128, 4), 256, 0, stream>>>(
      hb, w_f2, ffn_b2, nullptr, f2outb, nullptr, nullptr, nullptr, M, 512,
      2048, 5);
  // 9. out = LN2(x2 + ffn_out)
  add_ln_bb<<<dim3(M / 4), 256, 0, stream>>>(x2b, f2outb, ln2_g, ln2_b, outp);
}

// Round 8
// 416.159 us; speedup vs baseline: 1.0371x; 1.0371x over previous
//
#include <hip/hip_runtime.h>
#include <math.h>

// ---------------------------------------------------------------------------
// QuantumEncoderLayer R8: register-prefetch software pipeline (AITER-style).
//   gemm_mfma / attn_mfma: buffer_load tile k+1 -> VGPRs issued BEFORE the
//   compute phase of tile k; ds_write after the read-barrier. Global load
//   latency overlaps MFMA instead of sitting between the two barriers
//   (replaces global_load_lds, whose vmcnt(0)+barrier serialized every iter).
//   Same xor-swizzled conflict-free LDS layout, same 32 KB/block.
//   All else identical to R7.
// ---------------------------------------------------------------------------

typedef __bf16 bf16;
typedef bf16 bf16x8 __attribute__((ext_vector_type(8)));
typedef bf16 bf16x4 __attribute__((ext_vector_type(4)));
typedef float f32x4 __attribute__((ext_vector_type(4)));

__device__ __forceinline__ float waveAllSum(float v) {
#pragma unroll
  for (int m = 1; m < 64; m <<= 1) v += __shfl_xor(v, m, 64);
  return v;
}

__device__ __forceinline__ float fast_gelu(float v) {
  float u = 0.79788456080286536f * v * (1.0f + 0.044715f * v * v);
  return v / (1.0f + __expf(-2.0f * u));
}

// ---------------------------------------------------------------------------
__global__ __launch_bounds__(256) void cvt_all(
    const float* __restrict__ x, const float* __restrict__ w1,
    const float* __restrict__ w2, const float* __restrict__ w3,
    const float* __restrict__ w4, bf16* __restrict__ xb,
    bf16* __restrict__ b1, bf16* __restrict__ b2, bf16* __restrict__ b3,
    bf16* __restrict__ b4) {
  int i = blockIdx.x * 256 + threadIdx.x;
  const float* src;
  bf16* dst;
  int off;
  if (i < 2097152) {
    src = x; dst = xb; off = i;
  } else if (i < 2097152 + 196608) {
    src = w1; dst = b1; off = i - 2097152;
  } else if (i < 2097152 + 196608 + 65536) {
    src = w2; dst = b2; off = i - (2097152 + 196608);
  } else if (i < 2097152 + 196608 + 65536 + 262144) {
    src = w3; dst = b3; off = i - (2097152 + 196608 + 65536);
  } else {
    src = w4; dst = b4; off = i - (2097152 + 196608 + 65536 + 262144);
  }
  float4 v = ((const float4*)src)[off];
  bf16x4 o = {(bf16)v.x, (bf16)v.y, (bf16)v.z, (bf16)v.w};
  ((bf16x4*)dst)[off] = o;
}

// ---------------------------------------------------------------------------
// Wp (512x512 bf16 packed complex, interleaved cols: 2j -> Re_j, 2j+1 -> Im_j)
// ---------------------------------------------------------------------------
__global__ __launch_bounds__(256) void make_W(const float* __restrict__ qw,
                                              bf16* __restrict__ Wp) {
  __shared__ float gates[32 * 8];
  int tid = threadIdx.x, lane = tid & 63;
  if (tid < 32) {
    int l = tid >> 3, i = tid & 7;
    float ax = qw[l * 16 + i] * 0.5f;
    float az = qw[l * 16 + 8 + i] * 0.5f;
    float cx, sx, cz, sz;
    sincosf(ax, &sx, &cx);
    sincosf(az, &sz, &cz);
    float* g = gates + tid * 8;
    g[0] = cz * cx;   g[1] = -sz * cx;
    g[2] = -sz * sx;  g[3] = -cz * sx;
    g[4] = sz * sx;   g[5] = -cz * sx;
    g[6] = cz * cx;   g[7] = sz * cx;
  }
  __syncthreads();
  int k = blockIdx.x * 4 + (tid >> 6);

  float sr[4], si[4];
#pragma unroll
  for (int l = 0; l < 4; ++l) {
    sr[l] = (lane * 4 + l == k) ? 1.0f : 0.0f;
    si[l] = 0.0f;
  }

  auto gate = [&](int p, float u00r, float u00i, float u01r, float u01i,
                  float u10r, float u10i, float u11r, float u11i) {
    if (p >= 2) {
      int m = 1 << (p - 2);
      int b = (lane >> (p - 2)) & 1;
      float csr = b ? u11r : u00r;
      float csi = b ? u11i : u00i;
      float cor = b ? u10r : u01r;
      float coi = b ? u10i : u01i;
#pragma unroll
      for (int l = 0; l < 4; ++l) {
        float pr = __shfl_xor(sr[l], m, 64);
        float pi = __shfl_xor(si[l], m, 64);
        float nr = fmaf(csr, sr[l],
                        fmaf(-csi, si[l], fmaf(cor, pr, -coi * pi)));
        float ni = fmaf(csr, si[l],
                        fmaf(csi, sr[l], fmaf(cor, pi, coi * pr)));
        sr[l] = nr;
        si[l] = ni;
      }
    } else {
      float nr[4], ni[4];
#pragma unroll
      for (int l = 0; l < 4; ++l) {
        int b = (l >> p) & 1;
        int pl = l ^ (1 << p);
        float csr = b ? u11r : u00r;
        float csi = b ? u11i : u00i;
        float cor = b ? u10r : u01r;
        float coi = b ? u10i : u01i;
        nr[l] = fmaf(csr, sr[l],
                     fmaf(-csi, si[l], fmaf(cor, sr[pl], -coi * si[pl])));
        ni[l] = fmaf(csr, si[l],
                     fmaf(csi, sr[l], fmaf(cor, si[pl], coi * sr[pl])));
      }
#pragma unroll
      for (int l = 0; l < 4; ++l) {
        sr[l] = nr[l];
        si[l] = ni[l];
      }
    }
  };
  auto docnot = [&](int i) {
    int pc = 7 - i, pt = 6 - i;
    if (pt >= 2) {
      int ctrl = (lane >> (pc - 2)) & 1;
      int m = 1 << (pt - 2);
#pragma unroll
      for (int l = 0; l < 4; ++l) {
        float pr = __shfl_xor(sr[l], m, 64);
        float pi = __shfl_xor(si[l], m, 64);
        if (ctrl) {
          sr[l] = pr;
          si[l] = pi;
        }
      }
    } else if (pt == 1) {
      if (lane & 1) {
        float t;
        t = sr[0]; sr[0] = sr[2]; sr[2] = t;
        t = si[0]; si[0] = si[2]; si[2] = t;
        t = sr[1]; sr[1] = sr[3]; sr[3] = t;
        t = si[1]; si[1] = si[3]; si[3] = t;
      }
    } else {
      float t;
      t = sr[2]; sr[2] = sr[3]; sr[3] = t;
      t = si[2]; si[2] = si[3]; si[3] = t;
    }
  };

  for (int l = 0; l < 4; ++l) {
    for (int i = 0; i < 8; ++i) {
      const float* g = gates + (l * 8 + i) * 8;
      gate(7 - i, g[0], g[1], g[2], g[3], g[4], g[5], g[6], g[7]);
    }
    for (int i = 0; i < 7; ++i) docnot(i);
  }

#pragma unroll
  for (int l = 0; l < 4; ++l) {
    int j = lane * 4 + l;
    Wp[(2 * j) * 512 + k] = (bf16)sr[l];
    Wp[(2 * j) * 512 + 256 + k] = (bf16)(-si[l]);
    Wp[(2 * j + 1) * 512 + k] = (bf16)si[l];
    Wp[(2 * j + 1) * 512 + 256 + k] = (bf16)sr[l];
  }
}

// ---------------------------------------------------------------------------
__global__ __launch_bounds__(256) void make_Q(const float* __restrict__ qout_w,
                                              bf16* __restrict__ Q) {
  int t = blockIdx.x * 256 + threadIdx.x;
  int col = t >> 8, k = t & 255;
  float s = 0.f;
#pragma unroll
  for (int w = 0; w < 8; ++w) {
    float sg = ((k >> (7 - w)) & 1) ? -1.0f : 1.0f;
    s = fmaf(qout_w[col * 8 + w], sg, s);
  }
  Q[col * 256 + k] = (bf16)s;
}

// ---------------------------------------------------------------------------
// C[M,N] = A[M,K] @ W[N,K]^T (+bias). BK=64, xor-swizzled LDS, register-
// prefetch pipeline. modes: 1 gelu | 2 qkv-split | 4 residual | 5 plain |
// 6 prob-fused.  K multiple of 64.
// ---------------------------------------------------------------------------
__global__ __launch_bounds__(256) void gemm_mfma(
    const bf16* __restrict__ A, const bf16* __restrict__ W,
    const float* __restrict__ bias, const bf16* __restrict__ Xadd,
    bf16* __restrict__ Cb, bf16* __restrict__ qk, bf16* __restrict__ vT,
    bf16* __restrict__ prob, int M, int N, int K, int mode) {
  __shared__ __align__(16) bf16 As[128 * 64];
  __shared__ __align__(16) bf16 Bs[128 * 64];
  int tid = threadIdx.x;
  int lane = tid & 63, w = tid >> 6;
  int wr = w >> 1, wc = w & 1;
  int quad = lane >> 4, lc = lane & 15;
  long m0 = (long)blockIdx.x * 128;
  long n0 = (long)blockIdx.y * 128;
  f32x4 acc[4][4] = {};
  int sl0 = w * 256 + lane;

  const bf16* aSrc[4];
  const bf16* bSrc[4];
  int ldsOff[4];
#pragma unroll
  for (int c = 0; c < 4; ++c) {
    int slot = sl0 + c * 64;
    int row = slot >> 3, g = slot & 7;
    int sc = (g ^ (row & 7)) << 3;
    aSrc[c] = A + (m0 + row) * (long)K + sc;
    bSrc[c] = W + (n0 + row) * (long)K + sc;
    ldsOff[c] = slot << 3;
  }

  // prologue: load + write tile 0
  bf16x8 pa[4], pb[4];
#pragma unroll
  for (int c = 0; c < 4; ++c) {
    pa[c] = *(const bf16x8*)aSrc[c];
    pb[c] = *(const bf16x8*)bSrc[c];
    aSrc[c] += 64;
    bSrc[c] += 64;
  }
#pragma unroll
  for (int c = 0; c < 4; ++c) {
    *(bf16x8*)&As[ldsOff[c]] = pa[c];
    *(bf16x8*)&Bs[ldsOff[c]] = pb[c];
  }
  __syncthreads();

  int iters = K >> 6;
  for (int it = 0; it < iters; ++it) {
    bool more = (it + 1 < iters);
    if (more) {  // issue next-tile loads BEFORE compute (latency overlap)
#pragma unroll
      for (int c = 0; c < 4; ++c) {
        pa[c] = *(const bf16x8*)aSrc[c];
        pb[c] = *(const bf16x8*)bSrc[c];
        aSrc[c] += 64;
        bSrc[c] += 64;
      }
    }
#pragma unroll
    for (int t = 0; t < 2; ++t) {
      bf16x8 af[4], bfr[4];
      int pg = ((t * 4 + quad) ^ (lc & 7)) << 3;
#pragma unroll
      for (int i = 0; i < 4; ++i) {
        af[i] = *(const bf16x8*)&As[(wr * 64 + i * 16 + lc) * 64 + pg];
        bfr[i] = *(const bf16x8*)&Bs[(wc * 64 + i * 16 + lc) * 64 + pg];
      }
#pragma unroll
      for (int i = 0; i < 4; ++i)
#pragma unroll
        for (int j = 0; j < 4; ++j)
          acc[i][j] = __builtin_amdgcn_mfma_f32_16x16x32_bf16(
              af[i], bfr[j], acc[i][j], 0, 0, 0);
    }
    __syncthreads();  // all waves done reading current tile
    if (more) {
#pragma unroll
      for (int c = 0; c < 4; ++c) {
        *(bf16x8*)&As[ldsOff[c]] = pa[c];
        *(bf16x8*)&Bs[ldsOff[c]] = pb[c];
      }
    }
    __syncthreads();  // writes visible
  }

#pragma unroll
  for (int i = 0; i < 4; ++i) {
    long grow0 = m0 + wr * 64 + i * 16 + quad * 4;
#pragma unroll
    for (int j = 0; j < 4; ++j) {
      long col = n0 + wc * 64 + j * 16 + lc;
      float bv = (mode == 6) ? 0.f : bias[col];
      float v[4];
#pragma unroll
      for (int r = 0; r < 4; ++r) v[r] = acc[i][j][r] + bv;
      if (mode == 1) {
#pragma unroll
        for (int r = 0; r < 4; ++r)
          Cb[(grow0 + r) * N + col] = (bf16)fast_gelu(v[r]);
      } else if (mode == 4) {
#pragma unroll
        for (int r = 0; r < 4; ++r)
          Cb[(grow0 + r) * N + col] =
              (bf16)(v[r] + (float)Xadd[(grow0 + r) * N + col]);
      } else if (mode == 5) {
#pragma unroll
        for (int r = 0; r < 4; ++r) Cb[(grow0 + r) * N + col] = (bf16)v[r];
      } else if (mode == 6) {
        float pv[4];
#pragma unroll
        for (int r = 0; r < 4; ++r) pv[r] = v[r] * v[r];
#pragma unroll
        for (int r = 0; r < 4; ++r) pv[r] += __shfl_xor(pv[r], 1, 64);
        if (!(lc & 1)) {
          long pc = col >> 1;
#pragma unroll
          for (int r = 0; r < 4; ++r)
            prob[(grow0 + r) * 256 + pc] = (bf16)pv[r];
        }
      } else {  // mode 2
        if (col < 1024) {
#pragma unroll
          for (int r = 0; r < 4; ++r) qk[(grow0 + r) * 1024 + col] = (bf16)v[r];
        } else {
          int hh = (int)((col - 1024) >> 7);
          int dd = (int)((col - 1024) & 127);
          long bidx = grow0 >> 9;
          int s0 = (int)(grow0 & 511);
          bf16x4 pk = {(bf16)v[0], (bf16)v[1], (bf16)v[2], (bf16)v[3]};
          *(bf16x4*)&vT[(((bidx << 2) + hh) * 128 + dd) * 512 + s0] = pk;
        }
      }
    }
  }
}

// ---------------------------------------------------------------------------
// Flash attention (xor-swizzled, no-max softmax, __expf), register-prefetch
// pipeline.
// ---------------------------------------------------------------------------
__global__ __launch_bounds__(256) void attn_mfma(const bf16* __restrict__ qk,
                                                 const bf16* __restrict__ vT,
                                                 bf16* __restrict__ o) {
  __shared__ __align__(16) bf16 Ks[64 * 128];
  __shared__ __align__(16) bf16 Vt[128 * 64];
  __shared__ __align__(16) bf16 Ps[4][64 * 16];
  int tid = threadIdx.x, lane = tid & 63, w = tid >> 6;
  int quad = lane >> 4, lc = lane & 15;
  int bh = blockIdx.x, b = bh >> 2, h = bh & 3;
  int q0 = blockIdx.y * 64 + w * 16;
  const float scale = 0.08838834764831845f;

  bf16x8 qf[4];
  {
    const bf16* qp =
        qk + ((long)(b * 512 + q0 + lc)) * 1024 + h * 128 + quad * 8;
#pragma unroll
    for (int ks = 0; ks < 4; ++ks) qf[ks] = *(const bf16x8*)(qp + ks * 32);
  }
  f32x4 oacc[8] = {};
  float lrun[4] = {0.f, 0.f, 0.f, 0.f};

  const bf16* kbase = qk + (long)b * 512 * 1024 + 512 + h * 128;
  const bf16* vbase = vT + (long)bh * 128 * 512;
  int sl0 = w * 256 + lane;

  const bf16* kSrc[4];
  const bf16* vSrc[4];
  int kOff[4], vOff[4];
#pragma unroll
  for (int c = 0; c < 4; ++c) {
    int slot = sl0 + c * 64;
    {
      int row = slot >> 4, g = slot & 15;
      kSrc[c] = kbase + (long)row * 1024 + ((g ^ (row & 15)) << 3);
      kOff[c] = slot << 3;
    }
    {
      int row = slot >> 3, g = slot & 7;
      vSrc[c] = vbase + (long)row * 512 + ((g ^ (row & 7)) << 3);
      vOff[c] = slot << 3;
    }
  }

  // prologue: load + write tile 0
  bf16x8 pk_[4], pv_[4];
#pragma unroll
  for (int c = 0; c < 4; ++c) {
    pk_[c] = *(const bf16x8*)kSrc[c];
    pv_[c] = *(const bf16x8*)vSrc[c];
    kSrc[c] += 64 * 1024;
    vSrc[c] += 64;
  }
#pragma unroll
  for (int c = 0; c < 4; ++c) {
    *(bf16x8*)&Ks[kOff[c]] = pk_[c];
    *(bf16x8*)&Vt[vOff[c]] = pv_[c];
  }
  __syncthreads();

  for (int kt = 0; kt < 512; kt += 64) {
    bool more = (kt + 64 < 512);
    if (more) {
#pragma unroll
      for (int c = 0; c < 4; ++c) {
        pk_[c] = *(const bf16x8*)kSrc[c];
        pv_[c] = *(const bf16x8*)vSrc[c];
        kSrc[c] += 64 * 1024;
        vSrc[c] += 64;
      }
    }

    float p[4][4];
#pragma unroll
    for (int c = 0; c < 4; ++c) {
      f32x4 a = {};
#pragma unroll
      for (int ks = 0; ks < 4; ++ks) {
        bf16x8 kf = *(const bf16x8*)&Ks[(c * 16 + lc) * 128 +
                                        (((ks * 4 + quad) ^ lc) << 3)];
        a = __builtin_amdgcn_mfma_f32_16x16x32_bf16(qf[ks], kf, a, 0, 0, 0);
      }
#pragma unroll
      for (int r = 0; r < 4; ++r) p[c][r] = a[r] * scale;
    }

#pragma unroll
    for (int r = 0; r < 4; ++r) {
      float rs = 0.f;
#pragma unroll
      for (int c = 0; c < 4; ++c) {
        float e = __expf(p[c][r]);
        p[c][r] = e;
        rs += e;
      }
#pragma unroll
      for (int m = 1; m < 16; m <<= 1) rs += __shfl_xor(rs, m, 64);
      lrun[r] += rs;
    }

#pragma unroll
    for (int c = 0; c < 4; ++c) {
      bf16x4 pk = {(bf16)p[c][0], (bf16)p[c][1], (bf16)p[c][2], (bf16)p[c][3]};
      *(bf16x4*)&Ps[w][(c * 16 + lc) * 16 + ((quad ^ (lc & 3)) << 2)] = pk;
    }
    bf16x8 pf[2];
#pragma unroll
    for (int kc = 0; kc < 2; ++kc) {
      bf16x8 t;
#pragma unroll
      for (int jj = 0; jj < 8; ++jj) {
        int row = kc * 32 + quad * 8 + jj;
        t[jj] = Ps[w][row * 16 + (((lc >> 2) ^ (row & 3)) << 2) + (lc & 3)];
      }
      pf[kc] = t;
    }
#pragma unroll
    for (int n = 0; n < 8; ++n)
#pragma unroll
      for (int kc = 0; kc < 2; ++kc) {
        bf16x8 vf = *(const bf16x8*)&Vt[(n * 16 + lc) * 64 +
                                        (((kc * 4 + quad) ^ (lc & 7)) << 3)];
        oacc[n] =
            __builtin_amdgcn_mfma_f32_16x16x32_bf16(pf[kc], vf, oacc[n], 0, 0, 0);
      }

    __syncthreads();  // all waves done reading Ks/Vt
    if (more) {
#pragma unroll
      for (int c = 0; c < 4; ++c) {
        *(bf16x8*)&Ks[kOff[c]] = pk_[c];
        *(bf16x8*)&Vt[vOff[c]] = pv_[c];
      }
    }
    __syncthreads();
  }

  float linv[4];
#pragma unroll
  for (int r = 0; r < 4; ++r) linv[r] = 1.0f / lrun[r];
  bf16* op = o + ((long)(b * 512 + q0 + quad * 4)) * 512 + h * 128 + lc;
#pragma unroll
  for (int n = 0; n < 8; ++n)
#pragma unroll
    for (int r = 0; r < 4; ++r)
      op[(long)r * 512 + n * 16] = (bf16)(oacc[n][r] * linv[r]);
}

// ---------------------------------------------------------------------------
__global__ __launch_bounds__(256) void add_ln_bb(
    const bf16* __restrict__ a, const bf16* __restrict__ b,
    const float* __restrict__ g, const float* __restrict__ be,
    float* __restrict__ out) {
  long row = (blockIdx.x * 256 + threadIdx.x) >> 6;
  int lane = threadIdx.x & 63;
  const bf16* ar = a + row * 512;
  const bf16* br = b + row * 512;
  float v[8];
  float s = 0.f;
#pragma unroll
  for (int j = 0; j < 8; ++j) {
    int c = lane + 64 * j;
    v[j] = (float)ar[c] + (float)br[c];
    s += v[j];
  }
  s = waveAllSum(s);
  float mean = s * (1.0f / 512.0f);
  float var = 0.f;
#pragma unroll
  for (int j = 0; j < 8; ++j) {
    float d = v[j] - mean;
    var = fmaf(d, d, var);
  }
  var = waveAllSum(var);
  float rstd = rsqrtf(var * (1.0f / 512.0f) + 1e-5f);
  float* orow = out + row * 512;
#pragma unroll
  for (int j = 0; j < 8; ++j) {
    int c = lane + 64 * j;
    orow[c] = (v[j] - mean) * rstd * g[c] + be[c];
  }
}

// ---------------------------------------------------------------------------
__global__ __launch_bounds__(256) void quantum_pre(
    const bf16* __restrict__ xb, const bf16* __restrict__ attnpb,
    const float* __restrict__ g1, const float* __restrict__ b1,
    const float* __restrict__ g3, const float* __restrict__ b3,
    const float* __restrict__ qin_w, const float* __restrict__ qin_b,
    bf16* __restrict__ x1out, bf16* __restrict__ psi) {
  long row = (blockIdx.x * 256 + threadIdx.x) >> 6;
  int lane = threadIdx.x & 63;
  const bf16* xr = xb + row * 512;
  const bf16* ar = attnpb + row * 512;

  float x1v[8];
  {
    float s = 0.f;
#pragma unroll
    for (int j = 0; j < 8; ++j) {
      int c = lane + 64 * j;
      x1v[j] = (float)xr[c] + (float)ar[c];
      s += x1v[j];
    }
    s = waveAllSum(s);
    float mean = s * (1.0f / 512.0f);
    float var = 0.f;
#pragma unroll
    for (int j = 0; j < 8; ++j) {
      float d = x1v[j] - mean;
      var = fmaf(d, d, var);
    }
    var = waveAllSum(var);
    float rstd = rsqrtf(var * (1.0f / 512.0f) + 1e-5f);
#pragma unroll
    for (int j = 0; j < 8; ++j) {
      int c = lane + 64 * j;
      x1v[j] = (x1v[j] - mean) * rstd * g1[c] + b1[c];
    }
  }
  bf16* x1row = x1out + row * 512;
#pragma unroll
  for (int j = 0; j < 8; ++j) x1row[lane + 64 * j] = (bf16)x1v[j];

  float xn[8];
  {
    float s = 0.f;
#pragma unroll
    for (int j = 0; j < 8; ++j) s += x1v[j];
    s = waveAllSum(s);
    float mean = s * (1.0f / 512.0f);
    float var = 0.f;
#pragma unroll
    for (int j = 0; j < 8; ++j) {
      float d = x1v[j] - mean;
      var = fmaf(d, d, var);
    }
    var = waveAllSum(var);
    float rstd = rsqrtf(var * (1.0f / 512.0f) + 1e-5f);
#pragma unroll
    for (int j = 0; j < 8; ++j) {
      int c = lane + 64 * j;
      xn[j] = (x1v[j] - mean) * rstd * g3[c] + b3[c];
    }
  }

  float ang[8];
#pragma unroll
  for (int w = 0; w < 8; ++w) {
    float p = 0.f;
#pragma unroll
    for (int j = 0; j < 8; ++j)
      p = fmaf(xn[j], qin_w[w * 512 + lane + 64 * j], p);
    p = waveAllSum(p);
    ang[w] = p + qin_b[w];
  }

  float v0r[8], v0i[8], v1r[8];
#pragma unroll
  for (int i = 0; i < 8; ++i) {
    float h = ang[i] * 0.5f;
    float c, s;
    sincosf(h, &s, &c);
    v0r[i] = c * c;
    v0i[i] = -c * s;
    v1r[i] = s * s;
  }

  float Pr, Pi;
  {
    int bit0 = (lane >> 5) & 1;
    Pr = bit0 ? v1r[0] : v0r[0];
    Pi = v0i[0];
#pragma unroll
    for (int i = 1; i < 6; ++i) {
      int bit = (lane >> (5 - i)) & 1;
      float br = bit ? v1r[i] : v0r[i];
      float bi = v0i[i];
      float nr = Pr * br - Pi * bi;
      float ni = Pr * bi + Pi * br;
      Pr = nr;
      Pi = ni;
    }
  }

  bf16 rebuf[4], imbuf[4];
#pragma unroll
  for (int l = 0; l < 4; ++l) {
    int b6 = (l >> 1) & 1, b7 = l & 1;
    float br = b6 ? v1r[6] : v0r[6], bi = v0i[6];
    float tr = Pr * br - Pi * bi;
    float ti = Pr * bi + Pi * br;
    float cr = b7 ? v1r[7] : v0r[7], ci = v0i[7];
    float fr = tr * cr - ti * ci;
    float fi = tr * ci + ti * cr;
    rebuf[l] = (bf16)fr;
    imbuf[l] = (bf16)fi;
  }
  bf16* prow = psi + row * 512;
  *(bf16x4*)&prow[lane * 4] = *(bf16x4*)rebuf;
  *(bf16x4*)&prow[256 + lane * 4] = *(bf16x4*)imbuf;
}

// ---------------------------------------------------------------------------
extern "C" void kernel_launch(void* const* d_in, const int* in_sizes, int n_in,
                              void* d_out, int out_size, void* d_ws,
                              size_t ws_size, hipStream_t stream) {
  const float* x = (const float*)d_in[0];
  const float* attn_in_w = (const float*)d_in[1];
  const float* attn_in_b = (const float*)d_in[2];
  const float* attn_out_w = (const float*)d_in[3];
  const float* attn_out_b = (const float*)d_in[4];
  const float* ln1_g = (const float*)d_in[5];
  const float* ln1_b = (const float*)d_in[6];
  const float* ln2_g = (const float*)d_in[7];
  const float* ln2_b = (const float*)d_in[8];
  const float* ln3_g = (const float*)d_in[9];
  const float* ln3_b = (const float*)d_in[10];
  const float* qin_w = (const float*)d_in[11];
  const float* qin_b = (const float*)d_in[12];
  const float* qweights = (const float*)d_in[13];
  const float* qout_w = (const float*)d_in[14];
  const float* qout_b = (const float*)d_in[15];
  const float* ffn_w1 = (const float*)d_in[16];
  const float* ffn_b1 = (const float*)d_in[17];
  const float* ffn_w2 = (const float*)d_in[18];
  const float* ffn_b2 = (const float*)d_in[19];

  char* wsB = (char*)d_ws;
  bf16* qkb = (bf16*)(wsB);                      // 32 MB (B,S,1024)
  bf16* vtb = (bf16*)(wsB + (32L << 20));        // 16 MB (B,H,128,512)
  bf16* ob = (bf16*)(wsB + (48L << 20));         // 16 MB (B,S,512)
  bf16* hb = (bf16*)(wsB);                       // 64 MB overlay (qkv dead)
  bf16* attnpb = (bf16*)(wsB + (64L << 20));     // 16 MB
  bf16* psi = (bf16*)(wsB + (80L << 20));        // 16 MB
  bf16* x1b = (bf16*)(wsB + (96L << 20));        // 16 MB
  bf16* probb = (bf16*)(wsB + (112L << 20));     // 8 MB
  bf16* x2b = (bf16*)(wsB + (120L << 20));       // 16 MB
  bf16* f2outb = (bf16*)(wsB + (136L << 20));    // 16 MB
  bf16* xb = (bf16*)(wsB + (152L << 20));        // 16 MB
  bf16* w_in = (bf16*)(wsB + (168L << 20));      // 1.5 MB
  bf16* w_out = (bf16*)(wsB + (170L << 20));     // 0.5 MB
  bf16* w_f1 = (bf16*)(wsB + (171L << 20));      // 2 MB
  bf16* w_f2 = (bf16*)(wsB + (173L << 20));      // 2 MB
  bf16* Wp = (bf16*)(wsB + (176L << 20));        // 512 KB
  bf16* Qm = (bf16*)(wsB + (177L << 20));        // 256 KB

  const int M = 16384;
  float* outp = (float*)d_out;

  cvt_all<<<11264, 256, 0, stream>>>(x, attn_in_w, attn_out_w, ffn_w1, ffn_w2,
                                     xb, w_in, w_out, w_f1, w_f2);
  make_W<<<64, 256, 0, stream>>>(qweights, Wp);
  make_Q<<<512, 256, 0, stream>>>(qout_w, Qm);

  // 1. QKV projection (split epilogue)
  gemm_mfma<<<dim3(M / 128, 12), 256, 0, stream>>>(
      xb, w_in, attn_in_b, nullptr, nullptr, qkb, vtb, nullptr, M, 1536, 512,
      2);
  // 2. attention
  attn_mfma<<<dim3(128, 8), 256, 0, stream>>>(qkb, vtb, ob);
  // 3. output projection -> bf16
  gemm_mfma<<<dim3(M / 128, 4), 256, 0, stream>>>(
      ob, w_out, attn_out_b, nullptr, attnpb, nullptr, nullptr, nullptr, M,
      512, 512, 5);
  // 4. quantum_pre: x1b + psi
  quantum_pre<<<dim3(M / 4), 256, 0, stream>>>(xb, attnpb, ln1_g, ln1_b,
                                               ln3_g, ln3_b, qin_w, qin_b,
                                               x1b, psi);
  // 5. prob = |Psi @ Wp^T|^2 (fused epilogue)
  gemm_mfma<<<dim3(M / 128, 4), 256, 0, stream>>>(
      psi, Wp, nullptr, nullptr, nullptr, nullptr, nullptr, probb, M, 512,
      512, 6);
  // 6. x2 = x1 + prob @ Q^T + qout_b -> bf16
  gemm_mfma<<<dim3(M / 128, 4), 256, 0, stream>>>(
      probb, Qm, qout_b, x1b, x2b, nullptr, nullptr, nullptr, M, 512, 256, 4);
  // 7. h = fast_gelu(x2 @ ffn_w1^T + b1) -> bf16
  gemm_mfma<<<dim3(M / 128, 16), 256, 0, stream>>>(
      x2b, w_f1, ffn_b1, nullptr, hb, nullptr, nullptr, nullptr, M, 2048, 512,
      1);
  // 8. ffn_out = h @ ffn_w2^T + b2 -> bf16
  gemm_mfma<<<dim3(M / 128, 4), 256, 0, stream>>>(
      hb, w_f2, ffn_b2, nullptr, f2outb, nullptr, nullptr, nullptr, M, 512,
      2048, 5);
  // 9. out = LN2(x2 + ffn_out)
  add_ln_bb<<<dim3(M / 4), 256, 0, stream>>>(x2b, f2outb, ln2_g, ln2_b, outp);
}